// Round 4
// baseline (1284.183 us; speedup 1.0000x reference)
//
#include <hip/hip_runtime.h>
#include <hip/hip_bf16.h>

typedef __hip_bfloat16 bf16;
typedef __attribute__((ext_vector_type(8))) short short8;
typedef __attribute__((ext_vector_type(4))) float floatx4;

constexpr int Nn = 100000;   // nodes
constexpr int Ee = 640000;   // edges
constexpr int Pp = 640000;   // pos entries
constexpr int Gg = 128;      // graphs
constexpr int Ll = 3;        // layers
#define Dd 128
#define BN_EPS 1e-5f

__device__ __forceinline__ float b2f(bf16 x) { return __bfloat162float(x); }
__device__ __forceinline__ bf16 f2b(float x) { return __float2bfloat16(x); }

union U8 { uint4 u; bf16 h[8]; short8 s; };

// -------- estart[e] = lower_bound(pos_batch, e) --------
__global__ void k_estart(const int* __restrict__ pos_batch, int* __restrict__ estart) {
  int e = blockIdx.x * blockDim.x + threadIdx.x;
  if (e > Ee) return;
  int lo = 0, hi = Pp;
  while (lo < hi) { int mid = (lo + hi) >> 1; if (pos_batch[mid] < e) lo = mid + 1; else hi = mid; }
  estart[e] = lo;
}

// ======== counting-sort of edges by dst (pattern is layer-invariant) ========
__global__ void k_hist(const int* __restrict__ dst, int* __restrict__ cnt) {
  int e = blockIdx.x * blockDim.x + threadIdx.x;
  if (e >= Ee) return;
  atomicAdd(&cnt[dst[e]], 1);
}

__global__ void k_scanA(const int* __restrict__ cnt, int* __restrict__ rs,
                        int* __restrict__ chunkSum) {
  __shared__ int buf[1024];
  int tid = threadIdx.x;
  int i = blockIdx.x * 1024 + tid;
  int v = (i < Nn) ? cnt[i] : 0;
  buf[tid] = v;
  __syncthreads();
  for (int off = 1; off < 1024; off <<= 1) {
    int t = (tid >= off) ? buf[tid - off] : 0;
    __syncthreads();
    buf[tid] += t;
    __syncthreads();
  }
  if (i < Nn) rs[i] = buf[tid] - v;      // exclusive, chunk-local
  if (tid == 1023) chunkSum[blockIdx.x] = buf[1023];
}

__global__ void k_scanC(int* __restrict__ rs, const int* __restrict__ chunkSum) {
  __shared__ int offS;
  if (threadIdx.x == 0) {
    int o = 0;
    for (int j = 0; j < blockIdx.x; ++j) o += chunkSum[j];
    offS = o;
  }
  __syncthreads();
  int i = blockIdx.x * 1024 + threadIdx.x;
  if (i < Nn) rs[i] += offS;
}

__global__ void k_scatter(const int* __restrict__ dst, const int* __restrict__ rs,
                          int* __restrict__ cur, int* __restrict__ perm) {
  int e = blockIdx.x * blockDim.x + threadIdx.x;
  if (e >= Ee) return;
  int d = dst[e];
  int r = atomicAdd(&cur[d], 1);
  perm[rs[d] + r] = e;
}

__global__ void k_permcopy(const int* __restrict__ perm, const int* __restrict__ src,
                           const int* __restrict__ dst, const int* __restrict__ estart,
                           const float* __restrict__ eattr,
                           int* __restrict__ src_p, int* __restrict__ dst_p,
                           int2* __restrict__ rng_p, bf16* __restrict__ ea_p) {
  int i = blockIdx.x * blockDim.x + threadIdx.x;
  if (i >= Ee) return;
  int e = perm[i];
  src_p[i] = src[e];
  dst_p[i] = dst[e];
  rng_p[i] = make_int2(estart[e], estart[e + 1]);
  U8 o;
  #pragma unroll
  for (int j = 0; j < 7; ++j) o.h[j] = f2b(eattr[(size_t)e * 7 + j]);
  o.h[7] = f2b(1.0f);
  ((uint4*)ea_p)[i] = o.u;
}

// -------- pre-swizzle weights into MFMA B-fragment order: [kc][t][lane][8] --------
__global__ void k_prep(const float* __restrict__ zeW, const float* __restrict__ Wp,
                       const float* __restrict__ We, const float* __restrict__ be,
                       const float* __restrict__ bp,
                       const float* __restrict__ W1, const float* __restrict__ W2,
                       bf16* __restrict__ zeWsw, bf16* __restrict__ WpSw,
                       bf16* __restrict__ WeSw, bf16* __restrict__ W1sw,
                       bf16* __restrict__ W2sw) {
  int gid = blockIdx.x * blockDim.x + threadIdx.x;
  if (gid < 16384) {
    int i = gid;
    int j = i & 7, lane = (i >> 3) & 63, t = (i >> 9) & 7, kc = i >> 12;
    int k = kc * 32 + ((lane >> 4) * 8) + j, n = t * 16 + (lane & 15);
    zeWsw[i] = f2b(zeW[k * 128 + n]);
  }
  if (gid < 49152) {
    int l = gid / 16384, i = gid % 16384;
    int j = i & 7, lane = (i >> 3) & 63, t = (i >> 9) & 7, kc = i >> 12;
    int k = kc * 32 + ((lane >> 4) * 8) + j, n = t * 16 + (lane & 15);
    WpSw[gid] = f2b(Wp[l * 16384 + k * 128 + n]);
  }
  if (gid < 12288) {
    int l = gid / 4096, i = gid % 4096;
    int j = i & 7, lane = (i >> 3) & 63, t = i >> 9;
    int k = ((lane >> 4) * 8) + j, n = t * 16 + (lane & 15);
    float v = 0.f;
    if (k < 7) v = We[l * 896 + k * 128 + n];
    else if (k == 7) v = be[l * 128 + n] + bp[l * 128 + n];
    WeSw[gid] = f2b(v);
  }
  if (gid < 98304) {
    int l = gid / 32768, i = gid % 32768;
    int j = i & 7, lane = (i >> 3) & 63, t = (i >> 9) & 15, kc = i >> 13;
    int k = kc * 32 + ((lane >> 4) * 8) + j, n = t * 16 + (lane & 15);
    W1sw[gid] = f2b(W1[l * 32768 + k * 256 + n]);
  }
  if (gid < 98304) {
    int l = gid / 32768, i = gid % 32768;
    int j = i & 7, lane = (i >> 3) & 63, t = (i >> 9) & 7, kc = i >> 12;
    int k = kc * 32 + ((lane >> 4) * 8) + j, n = t * 16 + (lane & 15);
    W2sw[gid] = f2b(W2[l * 32768 + k * 128 + n]);
  }
}

// -------- fold every eval-mode BatchNorm into per-channel (scale, shift) --------
// fb layout (floats): sc1@0 sh1@128 sc2@256 sh2@384 Msc@512 Msh@1280
//                     Lsc@2048 Lsh@2432 V1sc@2816 V1sh@3328 V2sc@3840 V2sh@4096
__global__ void k_bnfold(const float* __restrict__ ze_bn1, const float* __restrict__ ze_b,
                         const float* __restrict__ ze_bn2,
                         const float* __restrict__ conv_b1, const float* __restrict__ conv_bn,
                         const float* __restrict__ conv_b2, const float* __restrict__ layer_bn,
                         const float* __restrict__ vn_b1, const float* __restrict__ vn_bn1,
                         const float* __restrict__ vn_b2, const float* __restrict__ vn_bn2,
                         float* __restrict__ fb) {
  int i = blockIdx.x * blockDim.x + threadIdx.x;
  if (i < 128) {
    float g = ze_bn1[i], b = ze_bn1[128 + i], m = ze_bn1[256 + i], v = ze_bn1[384 + i];
    float s = g * rsqrtf(v + BN_EPS);
    fb[i] = s; fb[128 + i] = b - m * s;
  } else if (i < 256) {
    int c = i - 128;
    float g = ze_bn2[c], b = ze_bn2[128 + c], m = ze_bn2[256 + c], v = ze_bn2[384 + c];
    float s = g * rsqrtf(v + BN_EPS);
    fb[256 + c] = s; fb[384 + c] = b - m * s + s * ze_b[c];
  } else if (i < 1024) {
    int j = i - 256; int l = j >> 8, c = j & 255;
    const float* bn = conv_bn + (size_t)l * 1024;
    float g = bn[c], b = bn[256 + c], m = bn[512 + c], v = bn[768 + c];
    float s = g * rsqrtf(v + BN_EPS);
    fb[512 + j] = s; fb[1280 + j] = b - m * s + s * conv_b1[l * 256 + c];
  } else if (i < 1408) {
    int j = i - 1024; int l = j >> 7, c = j & 127;
    const float* bn = layer_bn + (size_t)l * 512;
    float g = bn[c], b = bn[128 + c], m = bn[256 + c], v = bn[384 + c];
    float s = g * rsqrtf(v + BN_EPS);
    fb[2048 + j] = s; fb[2432 + j] = b - m * s + s * conv_b2[l * 128 + c];
  } else if (i < 1920) {
    int j = i - 1408; int l = j >> 8, c = j & 255;
    const float* bn = vn_bn1 + (size_t)l * 1024;
    float g = bn[c], b = bn[256 + c], m = bn[512 + c], v = bn[768 + c];
    float s = g * rsqrtf(v + BN_EPS);
    fb[2816 + j] = s; fb[3328 + j] = b - m * s + s * vn_b1[l * 256 + c];
  } else if (i < 2176) {
    int j = i - 1920; int l = j >> 7, c = j & 127;
    const float* bn = vn_bn2 + (size_t)l * 512;
    float g = bn[c], b = bn[128 + c], m = bn[256 + c], v = bn[384 + c];
    float s = g * rsqrtf(v + BN_EPS);
    fb[3840 + j] = s; fb[4096 + j] = b - m * s + s * vn_b2[l * 128 + c];
  }
}

__global__ void k_init_vn(const float* __restrict__ vn_emb, float* __restrict__ vn) {
  int gid = blockIdx.x * blockDim.x + threadIdx.x;
  if (gid >= Gg * 128) return;
  vn[gid] = vn_emb[gid & 127];
}

// -------- h_in = node_emb[x_node] + vn[batch]  (layer 0 only; later layers get
//          the vn-add fused into k_mlp_fused's epilogue) --------
__global__ void k_hin0(const int* __restrict__ x_node, const float* __restrict__ node_emb,
                       const float* __restrict__ vn, const int* __restrict__ batch,
                       bf16* __restrict__ h_in) {
  int gid = blockIdx.x * blockDim.x + threadIdx.x;
  if (gid >= Nn * 16) return;
  int n = gid >> 4, c = gid & 15;
  int x = x_node[n], b = batch[n];
  float4 a0 = ((const float4*)node_emb)[x * 32 + c * 2];
  float4 a1 = ((const float4*)node_emb)[x * 32 + c * 2 + 1];
  float4 v0 = ((const float4*)vn)[b * 32 + c * 2];
  float4 v1 = ((const float4*)vn)[b * 32 + c * 2 + 1];
  U8 o;
  o.h[0] = f2b(a0.x + v0.x); o.h[1] = f2b(a0.y + v0.y);
  o.h[2] = f2b(a0.z + v0.z); o.h[3] = f2b(a0.w + v0.w);
  o.h[4] = f2b(a1.x + v1.x); o.h[5] = f2b(a1.y + v1.y);
  o.h[6] = f2b(a1.z + v1.z); o.h[7] = f2b(a1.w + v1.w);
  ((uint4*)h_in)[gid] = o.u;
}

// -------- layer-0 edge kernel: full z-embedding + edge GEMMs + segsum; also
//          emits Z[E][128] bf16 (perm order) for layers 1..L-1 when store_z=1.
//          Doubles as the no-Z fallback (store_z=0, run every layer). --------
__global__ __launch_bounds__(256, 4) void k_edge_z(
    const int2* __restrict__ rng_perm, const int* __restrict__ pos_index,
    const float* __restrict__ pos_enc, const float* __restrict__ z_init,
    const float* __restrict__ fb, const bf16* __restrict__ zeWsw,
    const bf16* __restrict__ ea_p, const int* __restrict__ src_p,
    const int* __restrict__ dst_p, const bf16* __restrict__ h_in,
    const bf16* __restrict__ WpSw, const bf16* __restrict__ WeSw,
    bf16* __restrict__ Z, int store_z, float* agg) {
  __shared__ bf16 Az[64][136];
  __shared__ int dstS[64];
  int tid = threadIdx.x;
  int lane = tid & 63, wv = tid >> 6;
  int q = lane >> 4, ln = lane & 15;
  int e0 = blockIdx.x * 64;

  if (q == 0) dstS[16 * wv + ln] = dst_p[e0 + 16 * wv + ln];
  short8 af0 = {};
  if (q == 0) af0 = *(const short8*)(ea_p + (size_t)(e0 + 16 * wv + ln) * 8);

  // ---- zpool gather + folded-bn1/relu -> Az (wave-exclusive rows)
  {
    int r = lane >> 2, cc = lane & 3;
    int2 rg = rng_perm[e0 + 16 * wv + r];
    float acc[32];
    #pragma unroll
    for (int j = 0; j < 32; ++j) acc[j] = 0.f;
    for (int p = rg.x; p < rg.y; ++p) {
      int idx = pos_index[p];
      float w = pos_enc[p];
      #pragma unroll
      for (int qq = 0; qq < 8; ++qq) {
        float4 z4 = ((const float4*)z_init)[idx * 32 + cc * 8 + qq];
        acc[qq * 4 + 0] = fmaf(w, z4.x, acc[qq * 4 + 0]);
        acc[qq * 4 + 1] = fmaf(w, z4.y, acc[qq * 4 + 1]);
        acc[qq * 4 + 2] = fmaf(w, z4.z, acc[qq * 4 + 2]);
        acc[qq * 4 + 3] = fmaf(w, z4.w, acc[qq * 4 + 3]);
      }
    }
    #pragma unroll
    for (int qq = 0; qq < 4; ++qq) {
      U8 o;
      #pragma unroll
      for (int jj = 0; jj < 2; ++jj) {
        int col = cc * 32 + qq * 8 + jj * 4;
        float4 s4 = *(const float4*)&fb[col];
        float4 h4 = *(const float4*)&fb[128 + col];
        o.h[jj * 4 + 0] = f2b(fmaxf(0.f, fmaf(acc[qq * 8 + jj * 4 + 0], s4.x, h4.x)));
        o.h[jj * 4 + 1] = f2b(fmaxf(0.f, fmaf(acc[qq * 8 + jj * 4 + 1], s4.y, h4.y)));
        o.h[jj * 4 + 2] = f2b(fmaxf(0.f, fmaf(acc[qq * 8 + jj * 4 + 2], s4.z, h4.z)));
        o.h[jj * 4 + 3] = f2b(fmaxf(0.f, fmaf(acc[qq * 8 + jj * 4 + 3], s4.w, h4.w)));
      }
      *(uint4*)&Az[16 * wv + r][cc * 32 + qq * 8] = o.u;
    }
  }
  __builtin_amdgcn_wave_barrier();

  // ---- GEMM0: acc2 = ea @ WeSw
  floatx4 acc2[8] = {};
  #pragma unroll
  for (int t = 0; t < 8; ++t) {
    short8 bfr = *(const short8*)(WeSw + ((size_t)t * 64 + lane) * 8);
    acc2[t] = __builtin_amdgcn_mfma_f32_16x16x32_bf16(af0, bfr, acc2[t], 0, 0, 0);
  }
  // ---- GEMM1: acc1 = Az @ zeWsw
  floatx4 acc1[8] = {};
  #pragma unroll
  for (int kc = 0; kc < 4; ++kc) {
    short8 af = *(const short8*)&Az[16 * wv + ln][kc * 32 + q * 8];
    #pragma unroll
    for (int t = 0; t < 8; ++t) {
      short8 bfr = *(const short8*)(zeWsw + (((size_t)kc * 8 + t) * 64 + lane) * 8);
      acc1[t] = __builtin_amdgcn_mfma_f32_16x16x32_bf16(af, bfr, acc1[t], 0, 0, 0);
    }
  }
  // ---- z = relu(folded-bn2) -> Az rows (C-layout scatter)
  #pragma unroll
  for (int t = 0; t < 8; ++t) {
    int c = t * 16 + ln;
    float ss = fb[256 + c], hh = fb[384 + c];
    #pragma unroll
    for (int r = 0; r < 4; ++r)
      Az[16 * wv + q * 4 + r][c] = f2b(fmaxf(0.f, fmaf(acc1[t][r], ss, hh)));
  }
  __builtin_amdgcn_wave_barrier();
  // ---- GEMM2: acc2 += Az(z) @ WpSw
  #pragma unroll
  for (int kc = 0; kc < 4; ++kc) {
    short8 af = *(const short8*)&Az[16 * wv + ln][kc * 32 + q * 8];
    #pragma unroll
    for (int t = 0; t < 8; ++t) {
      short8 bfr = *(const short8*)(WpSw + (((size_t)kc * 8 + t) * 64 + lane) * 8);
      acc2[t] = __builtin_amdgcn_mfma_f32_16x16x32_bf16(af, bfr, acc2[t], 0, 0, 0);
    }
  }
  __builtin_amdgcn_wave_barrier();
  // ---- optional coalesced Z store (reads Az rows before h-gather overwrites)
  if (store_z) {
    #pragma unroll
    for (int p = 0; p < 4; ++p) {
      int row = 16 * wv + p * 4 + q;
      uint4 vv = *(const uint4*)&Az[row][ln * 8];
      ((uint4*)Z)[(size_t)(e0 + row) * 16 + ln] = vv;
    }
  }
  __builtin_amdgcn_wave_barrier();
  // ---- coalesced h_in gather into own rows of Az
  #pragma unroll
  for (int p = 0; p < 4; ++p) {
    int el = 16 * wv + p * 4 + q;
    int s = src_p[e0 + el];
    uint4 hh = ((const uint4*)h_in)[(size_t)s * 16 + ln];
    *(uint4*)&Az[el][ln * 8] = hh;
  }
  __builtin_amdgcn_wave_barrier();
  // ---- msg = relu(acc2 + h) -> Az
  #pragma unroll
  for (int t = 0; t < 8; ++t) {
    int c = t * 16 + ln;
    #pragma unroll
    for (int r = 0; r < 4; ++r) {
      int el = 16 * wv + q * 4 + r;
      Az[el][c] = f2b(fmaxf(0.f, acc2[t][r] + b2f(Az[el][c])));
    }
  }
  __builtin_amdgcn_wave_barrier();
  // ---- wave-level segmented sum (dst-sorted)
  {
    float s0 = 0.f, s1 = 0.f;
    int dprev = dstS[16 * wv];
    bool inside = false;
    #pragma unroll
    for (int j = 0; j < 16; ++j) {
      int dcur = dstS[16 * wv + j];
      if (dcur != dprev) {
        float* ap = agg + (size_t)dprev * Dd;
        if (inside) { ap[lane] = s0; ap[64 + lane] = s1; }
        else        { atomicAdd(ap + lane, s0); atomicAdd(ap + 64 + lane, s1); }
        s0 = 0.f; s1 = 0.f; dprev = dcur; inside = true;
      }
      s0 += b2f(Az[16 * wv + j][lane]);
      s1 += b2f(Az[16 * wv + j][64 + lane]);
    }
    float* ap = agg + (size_t)dprev * Dd;
    atomicAdd(ap + lane, s0);
    atomicAdd(ap + 64 + lane, s1);
  }
}

// -------- per-layer edge kernel (layers 1..): ea/Z A-frags straight from global --------
__global__ __launch_bounds__(256, 6) void k_edge_fused(
    const bf16* __restrict__ Z, const bf16* __restrict__ ea_p,
    const int* __restrict__ src_p, const int* __restrict__ dst_p,
    const bf16* __restrict__ h_in,
    const bf16* __restrict__ WpSw, const bf16* __restrict__ WeSw,
    float* agg) {
  __shared__ bf16 Az[64][136];   // h_in tile -> msg
  __shared__ int dstS[64];
  int tid = threadIdx.x;
  int lane = tid & 63, wv = tid >> 6;
  int q = lane >> 4, ln = lane & 15;
  int e0 = blockIdx.x * 64;

  if (q == 0) dstS[16 * wv + ln] = dst_p[e0 + 16 * wv + ln];

  short8 af0 = {};
  if (q == 0) af0 = *(const short8*)(ea_p + (size_t)(e0 + 16 * wv + ln) * 8);
  const bf16* zrow = Z + (size_t)(e0 + 16 * wv + ln) * 128 + q * 8;
  short8 zf0 = *(const short8*)(zrow);
  short8 zf1 = *(const short8*)(zrow + 32);
  short8 zf2 = *(const short8*)(zrow + 64);
  short8 zf3 = *(const short8*)(zrow + 96);

  // coalesced h_in gather into own rows of Az (independent of the GEMMs)
  #pragma unroll
  for (int p = 0; p < 4; ++p) {
    int el = 16 * wv + p * 4 + q;
    int s = src_p[e0 + el];
    uint4 hh = ((const uint4*)h_in)[(size_t)s * 16 + ln];
    *(uint4*)&Az[el][ln * 8] = hh;
  }

  floatx4 acc2[8] = {};
  #pragma unroll
  for (int t = 0; t < 8; ++t) {
    short8 bfr = *(const short8*)(WeSw + ((size_t)t * 64 + lane) * 8);
    acc2[t] = __builtin_amdgcn_mfma_f32_16x16x32_bf16(af0, bfr, acc2[t], 0, 0, 0);
  }
  #pragma unroll
  for (int t = 0; t < 8; ++t) {
    short8 bfr = *(const short8*)(WpSw + ((size_t)t * 64 + lane) * 8);
    acc2[t] = __builtin_amdgcn_mfma_f32_16x16x32_bf16(zf0, bfr, acc2[t], 0, 0, 0);
  }
  #pragma unroll
  for (int t = 0; t < 8; ++t) {
    short8 bfr = *(const short8*)(WpSw + (((size_t)8 + t) * 64 + lane) * 8);
    acc2[t] = __builtin_amdgcn_mfma_f32_16x16x32_bf16(zf1, bfr, acc2[t], 0, 0, 0);
  }
  #pragma unroll
  for (int t = 0; t < 8; ++t) {
    short8 bfr = *(const short8*)(WpSw + (((size_t)16 + t) * 64 + lane) * 8);
    acc2[t] = __builtin_amdgcn_mfma_f32_16x16x32_bf16(zf2, bfr, acc2[t], 0, 0, 0);
  }
  #pragma unroll
  for (int t = 0; t < 8; ++t) {
    short8 bfr = *(const short8*)(WpSw + (((size_t)24 + t) * 64 + lane) * 8);
    acc2[t] = __builtin_amdgcn_mfma_f32_16x16x32_bf16(zf3, bfr, acc2[t], 0, 0, 0);
  }
  __builtin_amdgcn_wave_barrier();
  #pragma unroll
  for (int t = 0; t < 8; ++t) {
    int c = t * 16 + ln;
    #pragma unroll
    for (int r = 0; r < 4; ++r) {
      int el = 16 * wv + q * 4 + r;
      Az[el][c] = f2b(fmaxf(0.f, acc2[t][r] + b2f(Az[el][c])));
    }
  }
  __builtin_amdgcn_wave_barrier();
  {
    float s0 = 0.f, s1 = 0.f;
    int dprev = dstS[16 * wv];
    bool inside = false;
    #pragma unroll
    for (int j = 0; j < 16; ++j) {
      int dcur = dstS[16 * wv + j];
      if (dcur != dprev) {
        float* ap = agg + (size_t)dprev * Dd;
        if (inside) { ap[lane] = s0; ap[64 + lane] = s1; }
        else        { atomicAdd(ap + lane, s0); atomicAdd(ap + 64 + lane, s1); }
        s0 = 0.f; s1 = 0.f; dprev = dcur; inside = true;
      }
      s0 += b2f(Az[16 * wv + j][lane]);
      s1 += b2f(Az[16 * wv + j][64 + lane]);
    }
    float* ap = agg + (size_t)dprev * Dd;
    atomicAdd(ap + lane, s0);
    atomicAdd(ap + 64 + lane, s1);
  }
}

// -------- fused node MLP. Also: re-zeroes its agg row band (zero_agg) so the next
//          layer's edge kernel finds agg clean, and adds vn[batch] to the output
//          (vn_next) so the separate k_hin pass is gone. agg may alias out_f:
//          per-block row bands are exclusive -> WAR-safe. --------
__global__ __launch_bounds__(256) void k_mlp_fused(
    const bf16* __restrict__ h_in, float* agg,
    const float* __restrict__ eps_arr, int l,
    const int* __restrict__ batch, const float* __restrict__ vn,
    const bf16* __restrict__ W1sw, const float* __restrict__ Msc, const float* __restrict__ Msh,
    const bf16* __restrict__ W2sw, const float* __restrict__ Lsc, const float* __restrict__ Lsh,
    int is_last, int zero_agg, bf16* __restrict__ out_b, float* out_f) {
  __shared__ bf16 R[4][16][280];
  int tid = threadIdx.x;
  int lane = tid & 63, wv = tid >> 6;
  int q = lane >> 4, ln = lane & 15;
  int r0 = blockIdx.x * 64;
  float epsv = 1.0f + eps_arr[l];
  {
    int r = lane >> 2, cc = lane & 3;
    int row = r0 + 16 * wv + r;
    float4 z4 = make_float4(0.f, 0.f, 0.f, 0.f);
    #pragma unroll
    for (int u = 0; u < 4; ++u) {
      int cb = cc * 4 + u;
      U8 o;
      if (row < Nn) {
        U8 hh; hh.u = ((const uint4*)h_in)[row * 16 + cb];
        float4 g0 = ((const float4*)agg)[row * 32 + cb * 2];
        float4 g1 = ((const float4*)agg)[row * 32 + cb * 2 + 1];
        o.h[0] = f2b(epsv * b2f(hh.h[0]) + g0.x); o.h[1] = f2b(epsv * b2f(hh.h[1]) + g0.y);
        o.h[2] = f2b(epsv * b2f(hh.h[2]) + g0.z); o.h[3] = f2b(epsv * b2f(hh.h[3]) + g0.w);
        o.h[4] = f2b(epsv * b2f(hh.h[4]) + g1.x); o.h[5] = f2b(epsv * b2f(hh.h[5]) + g1.y);
        o.h[6] = f2b(epsv * b2f(hh.h[6]) + g1.z); o.h[7] = f2b(epsv * b2f(hh.h[7]) + g1.w);
        if (zero_agg) {
          ((float4*)agg)[row * 32 + cb * 2] = z4;
          ((float4*)agg)[row * 32 + cb * 2 + 1] = z4;
        }
      } else {
        o.u.x = o.u.y = o.u.z = o.u.w = 0;
      }
      *(uint4*)&R[wv][r][cb * 8] = o.u;
    }
  }
  __builtin_amdgcn_wave_barrier();
  floatx4 acc1[16] = {};
  #pragma unroll
  for (int kc = 0; kc < 4; ++kc) {
    short8 af = *(const short8*)&R[wv][ln][kc * 32 + q * 8];
    #pragma unroll
    for (int t = 0; t < 16; ++t) {
      short8 bfr = *(const short8*)(W1sw + (size_t)l * 32768 + (((size_t)kc * 16 + t) * 64 + lane) * 8);
      acc1[t] = __builtin_amdgcn_mfma_f32_16x16x32_bf16(af, bfr, acc1[t], 0, 0, 0);
    }
  }
  #pragma unroll
  for (int t = 0; t < 16; ++t) {
    int c = t * 16 + ln;
    float ss = Msc[c], hh = Msh[c];
    #pragma unroll
    for (int r = 0; r < 4; ++r)
      R[wv][q * 4 + r][c] = f2b(fmaxf(0.f, fmaf(acc1[t][r], ss, hh)));
  }
  __builtin_amdgcn_wave_barrier();
  floatx4 acc2[8] = {};
  #pragma unroll
  for (int kc = 0; kc < 8; ++kc) {
    short8 af = *(const short8*)&R[wv][ln][kc * 32 + q * 8];
    #pragma unroll
    for (int t = 0; t < 8; ++t) {
      short8 bfr = *(const short8*)(W2sw + (size_t)l * 32768 + (((size_t)kc * 8 + t) * 64 + lane) * 8);
      acc2[t] = __builtin_amdgcn_mfma_f32_16x16x32_bf16(af, bfr, acc2[t], 0, 0, 0);
    }
  }
  // next-layer vn (already updated by k_vn_mlp launched before this kernel)
  int bb[4] = {0, 0, 0, 0};
  if (!is_last) {
    #pragma unroll
    for (int r = 0; r < 4; ++r) {
      int row = r0 + 16 * wv + q * 4 + r;
      if (row < Nn) bb[r] = batch[row];
    }
  }
  #pragma unroll
  for (int t = 0; t < 8; ++t) {
    int c = t * 16 + ln;
    float ss = Lsc[c], hh = Lsh[c];
    #pragma unroll
    for (int r = 0; r < 4; ++r) {
      int row = r0 + 16 * wv + q * 4 + r;
      if (row < Nn) {
        float x = fmaf(acc2[t][r], ss, hh);
        if (is_last) out_f[(size_t)row * Dd + c] = x;
        else         out_b[(size_t)row * Dd + c] = f2b(fmaxf(0.f, x) + vn[bb[r] * Dd + c]);
      }
    }
  }
}

// -------- vt = segment_sum(h_in, batch) --------
__global__ void k_vt_sum(const bf16* __restrict__ h_in, const int* __restrict__ batch,
                         float* __restrict__ vt) {
  int d = threadIdx.x;
  int chunk = (Nn + gridDim.x - 1) / gridDim.x;
  int r0 = blockIdx.x * chunk;
  int r1 = min(r0 + chunk, Nn);
  if (r0 >= r1) return;
  float acc = 0.f;
  int cur = batch[r0];
  for (int r = r0; r < r1; ++r) {
    int g = batch[r];
    if (g != cur) { atomicAdd(&vt[cur * Dd + d], acc); acc = 0.f; cur = g; }
    acc += b2f(h_in[r * Dd + d]);
  }
  atomicAdd(&vt[cur * Dd + d], acc);
}

// -------- virtual-node MLP (tiny; bn+bias folded) --------
__global__ __launch_bounds__(256) void k_vn_mlp(
    float* __restrict__ vn, const float* __restrict__ vt,
    const float* __restrict__ W1, const float* __restrict__ s1, const float* __restrict__ h1,
    const float* __restrict__ W2, const float* __restrict__ s2, const float* __restrict__ h2) {
  __shared__ float row[128];
  __shared__ float trow[256];
  int g = blockIdx.x;
  int tid = threadIdx.x;
  if (tid < 128) row[tid] = vt[g * Dd + tid] + vn[g * Dd + tid];
  __syncthreads();
  float acc = 0.f;
  for (int k = 0; k < 128; ++k) acc += row[k] * W1[k * 256 + tid];
  trow[tid] = fmaxf(0.f, fmaf(acc, s1[tid], h1[tid]));
  __syncthreads();
  if (tid < 128) {
    float acc2 = 0.f;
    for (int k = 0; k < 256; ++k) acc2 += trow[k] * W2[k * Dd + tid];
    vn[g * Dd + tid] = fmaxf(0.f, fmaf(acc2, s2[tid], h2[tid]));
  }
}

extern "C" void kernel_launch(void* const* d_in, const int* in_sizes, int n_in,
                              void* d_out, int out_size, void* d_ws, size_t ws_size,
                              hipStream_t stream) {
  const int*   x_node    = (const int*)  d_in[0];
  const int*   edge_idx  = (const int*)  d_in[1];
  const float* edge_attr = (const float*)d_in[2];
  const int*   batch     = (const int*)  d_in[3];
  const int*   pos_index = (const int*)  d_in[4];
  const float* pos_enc   = (const float*)d_in[5];
  const int*   pos_batch = (const int*)  d_in[6];
  const float* node_emb  = (const float*)d_in[7];
  const float* z_init    = (const float*)d_in[8];
  const float* ze_bn1    = (const float*)d_in[9];
  const float* ze_W      = (const float*)d_in[10];
  const float* ze_b      = (const float*)d_in[11];
  const float* ze_bn2    = (const float*)d_in[12];
  const float* vn_emb    = (const float*)d_in[13];
  const float* conv_We   = (const float*)d_in[14];
  const float* conv_be   = (const float*)d_in[15];
  const float* conv_Wp   = (const float*)d_in[16];
  const float* conv_bp   = (const float*)d_in[17];
  const float* conv_W1   = (const float*)d_in[18];
  const float* conv_b1   = (const float*)d_in[19];
  const float* conv_bn   = (const float*)d_in[20];
  const float* conv_W2   = (const float*)d_in[21];
  const float* conv_b2   = (const float*)d_in[22];
  const float* conv_eps  = (const float*)d_in[23];
  const float* layer_bn  = (const float*)d_in[24];
  const float* vn_W1     = (const float*)d_in[25];
  const float* vn_b1     = (const float*)d_in[26];
  const float* vn_bn1    = (const float*)d_in[27];
  const float* vn_W2     = (const float*)d_in[28];
  const float* vn_b2     = (const float*)d_in[29];
  const float* vn_bn2    = (const float*)d_in[30];

  // workspace — agg lives in d_out (row-aliased WAR-safe in k_mlp_fused).
  char* wb = (char*)d_ws;
  size_t o = 0;
  auto alloc = [&](size_t bytes) { void* p = wb + o; o += (bytes + 255) & ~255ull; return p; };
  bf16*  h_in     = (bf16*) alloc((size_t)Nn * 128 * 2);
  float* vn       = (float*)alloc((size_t)Gg * 128 * 4);
  float* vt       = (float*)alloc((size_t)Gg * 128 * 4);
  int*   estart   = (int*)  alloc((size_t)(Ee + 1) * 4);
  bf16*  zeWsw    = (bf16*) alloc(16384 * 2);
  bf16*  WpSw     = (bf16*) alloc(49152 * 2);
  bf16*  WeSw     = (bf16*) alloc(12288 * 2);
  bf16*  W1sw     = (bf16*) alloc(98304 * 2);
  bf16*  W2sw     = (bf16*) alloc(98304 * 2);
  float* fb       = (float*)alloc(4352 * 4);
  int*   cnt      = (int*)  alloc((size_t)Nn * 4);
  int*   rs       = (int*)  alloc((size_t)Nn * 4);
  int*   cur      = (int*)  alloc((size_t)Nn * 4);
  int*   chunkSum = (int*)  alloc(128 * 4);
  int*   perm     = (int*)  alloc((size_t)Ee * 4);
  int*   src_p    = (int*)  alloc((size_t)Ee * 4);
  int*   dst_p    = (int*)  alloc((size_t)Ee * 4);
  int2*  rng_p    = (int2*) alloc((size_t)Ee * 8);
  bf16*  ea_p     = (bf16*) alloc((size_t)Ee * 8 * 2);
  bf16*  Z        = (bf16*) alloc((size_t)Ee * 128 * 2);   // 164 MB, allocated last
  float* agg      = (float*)d_out;                          // N*128 f32 == out buffer
  bool useZ = (o <= ws_size);                               // hoisted path only if ws fits

  const int* src = edge_idx;
  const int* dst = edge_idx + Ee;

  // ---- once-per-launch precompute (layer-invariant) ----
  k_estart<<<(Ee + 256) / 256, 256, 0, stream>>>(pos_batch, estart);
  hipMemsetAsync(cnt, 0, (size_t)Nn * 4, stream);
  hipMemsetAsync(cur, 0, (size_t)Nn * 4, stream);
  k_hist<<<(Ee + 255) / 256, 256, 0, stream>>>(dst, cnt);
  int nchunk = (Nn + 1023) / 1024;
  k_scanA<<<nchunk, 1024, 0, stream>>>(cnt, rs, chunkSum);
  k_scanC<<<nchunk, 1024, 0, stream>>>(rs, chunkSum);
  k_scatter<<<(Ee + 255) / 256, 256, 0, stream>>>(dst, rs, cur, perm);
  k_permcopy<<<(Ee + 255) / 256, 256, 0, stream>>>(perm, src, dst, estart, edge_attr,
                                                   src_p, dst_p, rng_p, ea_p);
  k_prep<<<(98304 + 255) / 256, 256, 0, stream>>>(ze_W, conv_Wp, conv_We, conv_be, conv_bp,
                                                  conv_W1, conv_W2,
                                                  zeWsw, WpSw, WeSw, W1sw, W2sw);
  k_bnfold<<<9, 256, 0, stream>>>(ze_bn1, ze_b, ze_bn2, conv_b1, conv_bn,
                                  conv_b2, layer_bn, vn_b1, vn_bn1, vn_b2, vn_bn2, fb);
  k_init_vn<<<(Gg * 128 + 255) / 256, 256, 0, stream>>>(vn_emb, vn);
  k_hin0<<<(Nn * 16 + 255) / 256, 256, 0, stream>>>(x_node, node_emb, vn, batch, h_in);
  hipMemsetAsync(agg, 0, (size_t)Nn * 128 * 4, stream);

  int mblocks = (Nn + 63) / 64;
  for (int l = 0; l < Ll; ++l) {
    if (l == 0 || !useZ)
      k_edge_z<<<Ee / 64, 256, 0, stream>>>(rng_p, pos_index, pos_enc, z_init,
          fb, zeWsw, ea_p, src_p, dst_p, h_in,
          WpSw + (size_t)l * 16384, WeSw + (size_t)l * 4096,
          Z, (l == 0 && useZ) ? 1 : 0, agg);
    else
      k_edge_fused<<<Ee / 64, 256, 0, stream>>>(Z, ea_p, src_p, dst_p, h_in,
          WpSw + (size_t)l * 16384, WeSw + (size_t)l * 4096, agg);
    if (l < Ll - 1) {
      hipMemsetAsync(vt, 0, (size_t)Gg * 128 * 4, stream);
      k_vt_sum<<<1024, 128, 0, stream>>>(h_in, batch, vt);
      k_vn_mlp<<<Gg, 256, 0, stream>>>(vn, vt,
          vn_W1 + (size_t)l * 128 * 256, fb + 2816 + l * 256, fb + 3328 + l * 256,
          vn_W2 + (size_t)l * 256 * 128, fb + 3840 + l * 128, fb + 4096 + l * 128);
    }
    k_mlp_fused<<<mblocks, 256, 0, stream>>>(h_in, agg, conv_eps, l, batch, vn,
        W1sw, fb + 512 + l * 256, fb + 1280 + l * 256,
        W2sw, fb + 2048 + l * 128, fb + 2432 + l * 128,
        (l == Ll - 1) ? 1 : 0, (l < Ll - 1) ? 1 : 0, h_in, (float*)d_out);
  }
}

// Round 5
// 1082.375 us; speedup vs baseline: 1.1864x; 1.1864x over previous
//
#include <hip/hip_runtime.h>
#include <hip/hip_bf16.h>

typedef __hip_bfloat16 bf16;
typedef __attribute__((ext_vector_type(8))) short short8;
typedef __attribute__((ext_vector_type(4))) float floatx4;

constexpr int Nn = 100000;   // nodes
constexpr int Ee = 640000;   // edges
constexpr int Pp = 640000;   // pos entries
constexpr int Gg = 128;      // graphs
constexpr int Ll = 3;        // layers
#define Dd 128
#define BN_EPS 1e-5f

__device__ __forceinline__ float b2f(bf16 x) { return __bfloat162float(x); }
__device__ __forceinline__ bf16 f2b(float x) { return __float2bfloat16(x); }
#define MFMA16 __builtin_amdgcn_mfma_f32_16x16x32_bf16

union U8 { uint4 u; bf16 h[8]; short8 s; };

// -------- estart[e] = lower_bound(pos_batch, e) --------
__global__ void k_estart(const int* __restrict__ pos_batch, int* __restrict__ estart) {
  int e = blockIdx.x * blockDim.x + threadIdx.x;
  if (e > Ee) return;
  int lo = 0, hi = Pp;
  while (lo < hi) { int mid = (lo + hi) >> 1; if (pos_batch[mid] < e) lo = mid + 1; else hi = mid; }
  estart[e] = lo;
}

// ======== counting-sort of edges by dst (pattern is layer-invariant) ========
__global__ void k_hist(const int* __restrict__ dst, int* __restrict__ cnt) {
  int e = blockIdx.x * blockDim.x + threadIdx.x;
  if (e >= Ee) return;
  atomicAdd(&cnt[dst[e]], 1);
}

__global__ void k_scanA(const int* __restrict__ cnt, int* __restrict__ rs,
                        int* __restrict__ chunkSum) {
  __shared__ int buf[1024];
  int tid = threadIdx.x;
  int i = blockIdx.x * 1024 + tid;
  int v = (i < Nn) ? cnt[i] : 0;
  buf[tid] = v;
  __syncthreads();
  for (int off = 1; off < 1024; off <<= 1) {
    int t = (tid >= off) ? buf[tid - off] : 0;
    __syncthreads();
    buf[tid] += t;
    __syncthreads();
  }
  if (i < Nn) rs[i] = buf[tid] - v;      // exclusive, chunk-local
  if (tid == 1023) chunkSum[blockIdx.x] = buf[1023];
}

__global__ void k_scanC(int* __restrict__ rs, const int* __restrict__ chunkSum) {
  __shared__ int offS;
  if (threadIdx.x == 0) {
    int o = 0;
    for (int j = 0; j < blockIdx.x; ++j) o += chunkSum[j];
    offS = o;
  }
  __syncthreads();
  int i = blockIdx.x * 1024 + threadIdx.x;
  if (i < Nn) rs[i] += offS;
}

__global__ void k_scatter(const int* __restrict__ dst, const int* __restrict__ rs,
                          int* __restrict__ cur, int* __restrict__ perm) {
  int e = blockIdx.x * blockDim.x + threadIdx.x;
  if (e >= Ee) return;
  int d = dst[e];
  int r = atomicAdd(&cur[d], 1);
  perm[rs[d] + r] = e;
}

__global__ void k_permcopy(const int* __restrict__ perm, const int* __restrict__ src,
                           const int* __restrict__ dst, const int* __restrict__ estart,
                           const float* __restrict__ eattr,
                           int* __restrict__ src_p, int* __restrict__ dst_p,
                           int2* __restrict__ rng_p, bf16* __restrict__ ea_p) {
  int i = blockIdx.x * blockDim.x + threadIdx.x;
  if (i >= Ee) return;
  int e = perm[i];
  src_p[i] = src[e];
  dst_p[i] = dst[e];
  rng_p[i] = make_int2(estart[e], estart[e + 1]);
  U8 o;
  #pragma unroll
  for (int j = 0; j < 7; ++j) o.h[j] = f2b(eattr[(size_t)e * 7 + j]);
  o.h[7] = f2b(1.0f);
  ((uint4*)ea_p)[i] = o.u;
}

// -------- pre-swizzle weights into MFMA B-fragment order: [kc][t][lane][8] --------
__global__ void k_prep(const float* __restrict__ zeW, const float* __restrict__ Wp,
                       const float* __restrict__ We, const float* __restrict__ be,
                       const float* __restrict__ bp,
                       const float* __restrict__ W1, const float* __restrict__ W2,
                       bf16* __restrict__ zeWsw, bf16* __restrict__ WpSw,
                       bf16* __restrict__ WeSw, bf16* __restrict__ W1sw,
                       bf16* __restrict__ W2sw) {
  int gid = blockIdx.x * blockDim.x + threadIdx.x;
  if (gid < 16384) {
    int i = gid;
    int j = i & 7, lane = (i >> 3) & 63, t = (i >> 9) & 7, kc = i >> 12;
    int k = kc * 32 + ((lane >> 4) * 8) + j, n = t * 16 + (lane & 15);
    zeWsw[i] = f2b(zeW[k * 128 + n]);
  }
  if (gid < 49152) {
    int l = gid / 16384, i = gid % 16384;
    int j = i & 7, lane = (i >> 3) & 63, t = (i >> 9) & 7, kc = i >> 12;
    int k = kc * 32 + ((lane >> 4) * 8) + j, n = t * 16 + (lane & 15);
    WpSw[gid] = f2b(Wp[l * 16384 + k * 128 + n]);
  }
  if (gid < 12288) {
    int l = gid / 4096, i = gid % 4096;
    int j = i & 7, lane = (i >> 3) & 63, t = i >> 9;
    int k = ((lane >> 4) * 8) + j, n = t * 16 + (lane & 15);
    float v = 0.f;
    if (k < 7) v = We[l * 896 + k * 128 + n];
    else if (k == 7) v = be[l * 128 + n] + bp[l * 128 + n];
    WeSw[gid] = f2b(v);
  }
  if (gid < 98304) {
    int l = gid / 32768, i = gid % 32768;
    int j = i & 7, lane = (i >> 3) & 63, t = (i >> 9) & 15, kc = i >> 13;
    int k = kc * 32 + ((lane >> 4) * 8) + j, n = t * 16 + (lane & 15);
    W1sw[gid] = f2b(W1[l * 32768 + k * 256 + n]);
  }
  if (gid < 98304) {
    int l = gid / 32768, i = gid % 32768;
    int j = i & 7, lane = (i >> 3) & 63, t = (i >> 9) & 7, kc = i >> 12;
    int k = kc * 32 + ((lane >> 4) * 8) + j, n = t * 16 + (lane & 15);
    W2sw[gid] = f2b(W2[l * 32768 + k * 128 + n]);
  }
}

// -------- fold every eval-mode BatchNorm into per-channel (scale, shift) --------
// fb layout (floats): sc1@0 sh1@128 sc2@256 sh2@384 Msc@512 Msh@1280
//                     Lsc@2048 Lsh@2432 V1sc@2816 V1sh@3328 V2sc@3840 V2sh@4096
__global__ void k_bnfold(const float* __restrict__ ze_bn1, const float* __restrict__ ze_b,
                         const float* __restrict__ ze_bn2,
                         const float* __restrict__ conv_b1, const float* __restrict__ conv_bn,
                         const float* __restrict__ conv_b2, const float* __restrict__ layer_bn,
                         const float* __restrict__ vn_b1, const float* __restrict__ vn_bn1,
                         const float* __restrict__ vn_b2, const float* __restrict__ vn_bn2,
                         float* __restrict__ fb) {
  int i = blockIdx.x * blockDim.x + threadIdx.x;
  if (i < 128) {
    float g = ze_bn1[i], b = ze_bn1[128 + i], m = ze_bn1[256 + i], v = ze_bn1[384 + i];
    float s = g * rsqrtf(v + BN_EPS);
    fb[i] = s; fb[128 + i] = b - m * s;
  } else if (i < 256) {
    int c = i - 128;
    float g = ze_bn2[c], b = ze_bn2[128 + c], m = ze_bn2[256 + c], v = ze_bn2[384 + c];
    float s = g * rsqrtf(v + BN_EPS);
    fb[256 + c] = s; fb[384 + c] = b - m * s + s * ze_b[c];
  } else if (i < 1024) {
    int j = i - 256; int l = j >> 8, c = j & 255;
    const float* bn = conv_bn + (size_t)l * 1024;
    float g = bn[c], b = bn[256 + c], m = bn[512 + c], v = bn[768 + c];
    float s = g * rsqrtf(v + BN_EPS);
    fb[512 + j] = s; fb[1280 + j] = b - m * s + s * conv_b1[l * 256 + c];
  } else if (i < 1408) {
    int j = i - 1024; int l = j >> 7, c = j & 127;
    const float* bn = layer_bn + (size_t)l * 512;
    float g = bn[c], b = bn[128 + c], m = bn[256 + c], v = bn[384 + c];
    float s = g * rsqrtf(v + BN_EPS);
    fb[2048 + j] = s; fb[2432 + j] = b - m * s + s * conv_b2[l * 128 + c];
  } else if (i < 1920) {
    int j = i - 1408; int l = j >> 8, c = j & 255;
    const float* bn = vn_bn1 + (size_t)l * 1024;
    float g = bn[c], b = bn[256 + c], m = bn[512 + c], v = bn[768 + c];
    float s = g * rsqrtf(v + BN_EPS);
    fb[2816 + j] = s; fb[3328 + j] = b - m * s + s * vn_b1[l * 256 + c];
  } else if (i < 2176) {
    int j = i - 1920; int l = j >> 7, c = j & 127;
    const float* bn = vn_bn2 + (size_t)l * 512;
    float g = bn[c], b = bn[128 + c], m = bn[256 + c], v = bn[384 + c];
    float s = g * rsqrtf(v + BN_EPS);
    fb[3840 + j] = s; fb[4096 + j] = b - m * s + s * vn_b2[l * 128 + c];
  }
}

__global__ void k_init_vn(const float* __restrict__ vn_emb, float* __restrict__ vn) {
  int gid = blockIdx.x * blockDim.x + threadIdx.x;
  if (gid >= Gg * 128) return;
  vn[gid] = vn_emb[gid & 127];
}

// -------- h_in = node_emb[x_node] + vn[batch]  (layer 0 only) --------
__global__ void k_hin0(const int* __restrict__ x_node, const float* __restrict__ node_emb,
                       const float* __restrict__ vn, const int* __restrict__ batch,
                       bf16* __restrict__ h_in) {
  int gid = blockIdx.x * blockDim.x + threadIdx.x;
  if (gid >= Nn * 16) return;
  int n = gid >> 4, c = gid & 15;
  int x = x_node[n], b = batch[n];
  float4 a0 = ((const float4*)node_emb)[x * 32 + c * 2];
  float4 a1 = ((const float4*)node_emb)[x * 32 + c * 2 + 1];
  float4 v0 = ((const float4*)vn)[b * 32 + c * 2];
  float4 v1 = ((const float4*)vn)[b * 32 + c * 2 + 1];
  U8 o;
  o.h[0] = f2b(a0.x + v0.x); o.h[1] = f2b(a0.y + v0.y);
  o.h[2] = f2b(a0.z + v0.z); o.h[3] = f2b(a0.w + v0.w);
  o.h[4] = f2b(a1.x + v1.x); o.h[5] = f2b(a1.y + v1.y);
  o.h[6] = f2b(a1.z + v1.z); o.h[7] = f2b(a1.w + v1.w);
  ((uint4*)h_in)[gid] = o.u;
}

// -------- layer-0 edge kernel: z-embedding + edge GEMMs + segsum; emits Z when
//          store_z=1. GEMM order chosen so acc1/acc2 live ranges are DISJOINT
//          (unified VGPR/AGPR file: peak 32 acc regs instead of 64). --------
__global__ __launch_bounds__(256, 4) void k_edge_z(
    const int2* __restrict__ rng_perm, const int* __restrict__ pos_index,
    const float* __restrict__ pos_enc, const float* __restrict__ z_init,
    const float* __restrict__ fb, const bf16* __restrict__ zeWsw,
    const bf16* __restrict__ ea_p, const int* __restrict__ src_p,
    const int* __restrict__ dst_p, const bf16* __restrict__ h_in,
    const bf16* __restrict__ WpSw, const bf16* __restrict__ WeSw,
    bf16* __restrict__ Z, int store_z, float* agg) {
  __shared__ bf16 Az[64][136];
  __shared__ int dstS[64];
  int tid = threadIdx.x;
  int lane = tid & 63, wv = tid >> 6;
  int q = lane >> 4, ln = lane & 15;
  int e0 = blockIdx.x * 64;

  if (q == 0) dstS[16 * wv + ln] = dst_p[e0 + 16 * wv + ln];
  short8 af0 = {};
  if (q == 0) af0 = *(const short8*)(ea_p + (size_t)(e0 + 16 * wv + ln) * 8);

  // ---- zpool gather + folded-bn1/relu -> Az (wave-exclusive rows)
  {
    int r = lane >> 2, cc = lane & 3;
    int2 rg = rng_perm[e0 + 16 * wv + r];
    float acc[32];
    #pragma unroll
    for (int j = 0; j < 32; ++j) acc[j] = 0.f;
    for (int p = rg.x; p < rg.y; ++p) {
      int idx = pos_index[p];
      float w = pos_enc[p];
      #pragma unroll
      for (int qq = 0; qq < 8; ++qq) {
        float4 z4 = ((const float4*)z_init)[idx * 32 + cc * 8 + qq];
        acc[qq * 4 + 0] = fmaf(w, z4.x, acc[qq * 4 + 0]);
        acc[qq * 4 + 1] = fmaf(w, z4.y, acc[qq * 4 + 1]);
        acc[qq * 4 + 2] = fmaf(w, z4.z, acc[qq * 4 + 2]);
        acc[qq * 4 + 3] = fmaf(w, z4.w, acc[qq * 4 + 3]);
      }
    }
    #pragma unroll
    for (int qq = 0; qq < 4; ++qq) {
      U8 o;
      #pragma unroll
      for (int jj = 0; jj < 2; ++jj) {
        int col = cc * 32 + qq * 8 + jj * 4;
        float4 s4 = *(const float4*)&fb[col];
        float4 h4 = *(const float4*)&fb[128 + col];
        o.h[jj * 4 + 0] = f2b(fmaxf(0.f, fmaf(acc[qq * 8 + jj * 4 + 0], s4.x, h4.x)));
        o.h[jj * 4 + 1] = f2b(fmaxf(0.f, fmaf(acc[qq * 8 + jj * 4 + 1], s4.y, h4.y)));
        o.h[jj * 4 + 2] = f2b(fmaxf(0.f, fmaf(acc[qq * 8 + jj * 4 + 2], s4.z, h4.z)));
        o.h[jj * 4 + 3] = f2b(fmaxf(0.f, fmaf(acc[qq * 8 + jj * 4 + 3], s4.w, h4.w)));
      }
      *(uint4*)&Az[16 * wv + r][cc * 32 + qq * 8] = o.u;
    }
  }
  __builtin_amdgcn_wave_barrier();

  // ---- GEMM1 first: acc1 = Az @ zeWsw (acc1 dies at the z-scatter)
  {
    floatx4 acc1[8] = {};
    #pragma unroll
    for (int kc = 0; kc < 4; ++kc) {
      short8 af = *(const short8*)&Az[16 * wv + ln][kc * 32 + q * 8];
      #pragma unroll
      for (int t = 0; t < 8; ++t) {
        short8 bfr = *(const short8*)(zeWsw + (((size_t)kc * 8 + t) * 64 + lane) * 8);
        acc1[t] = MFMA16(af, bfr, acc1[t], 0, 0, 0);
      }
    }
    __builtin_amdgcn_wave_barrier();
    // z = relu(folded-bn2) -> Az rows (C-layout scatter)
    #pragma unroll
    for (int t = 0; t < 8; ++t) {
      int c = t * 16 + ln;
      float ss = fb[256 + c], hh = fb[384 + c];
      #pragma unroll
      for (int r = 0; r < 4; ++r)
        Az[16 * wv + q * 4 + r][c] = f2b(fmaxf(0.f, fmaf(acc1[t][r], ss, hh)));
    }
  }
  __builtin_amdgcn_wave_barrier();
  // ---- GEMM0 + GEMM2: acc2 = ea @ WeSw + z @ WpSw (acc1 regs are free now)
  floatx4 acc2[8] = {};
  #pragma unroll
  for (int t = 0; t < 8; ++t) {
    short8 bfr = *(const short8*)(WeSw + ((size_t)t * 64 + lane) * 8);
    acc2[t] = MFMA16(af0, bfr, acc2[t], 0, 0, 0);
  }
  #pragma unroll
  for (int kc = 0; kc < 4; ++kc) {
    short8 af = *(const short8*)&Az[16 * wv + ln][kc * 32 + q * 8];
    #pragma unroll
    for (int t = 0; t < 8; ++t) {
      short8 bfr = *(const short8*)(WpSw + (((size_t)kc * 8 + t) * 64 + lane) * 8);
      acc2[t] = MFMA16(af, bfr, acc2[t], 0, 0, 0);
    }
  }
  __builtin_amdgcn_wave_barrier();
  // ---- optional coalesced Z store (reads Az z rows before h-gather overwrites)
  if (store_z) {
    #pragma unroll
    for (int p = 0; p < 4; ++p) {
      int row = 16 * wv + p * 4 + q;
      uint4 vv = *(const uint4*)&Az[row][ln * 8];
      ((uint4*)Z)[(size_t)(e0 + row) * 16 + ln] = vv;
    }
  }
  __builtin_amdgcn_wave_barrier();
  // ---- coalesced h_in gather into own rows of Az
  #pragma unroll
  for (int p = 0; p < 4; ++p) {
    int el = 16 * wv + p * 4 + q;
    int s = src_p[e0 + el];
    uint4 hh = ((const uint4*)h_in)[(size_t)s * 16 + ln];
    *(uint4*)&Az[el][ln * 8] = hh;
  }
  __builtin_amdgcn_wave_barrier();
  // ---- msg = relu(acc2 + h) -> Az
  #pragma unroll
  for (int t = 0; t < 8; ++t) {
    int c = t * 16 + ln;
    #pragma unroll
    for (int r = 0; r < 4; ++r) {
      int el = 16 * wv + q * 4 + r;
      Az[el][c] = f2b(fmaxf(0.f, acc2[t][r] + b2f(Az[el][c])));
    }
  }
  __builtin_amdgcn_wave_barrier();
  // ---- wave-level segmented sum (dst-sorted)
  {
    float s0 = 0.f, s1 = 0.f;
    int dprev = dstS[16 * wv];
    bool inside = false;
    #pragma unroll
    for (int j = 0; j < 16; ++j) {
      int dcur = dstS[16 * wv + j];
      if (dcur != dprev) {
        float* ap = agg + (size_t)dprev * Dd;
        if (inside) { ap[lane] = s0; ap[64 + lane] = s1; }
        else        { atomicAdd(ap + lane, s0); atomicAdd(ap + 64 + lane, s1); }
        s0 = 0.f; s1 = 0.f; dprev = dcur; inside = true;
      }
      s0 += b2f(Az[16 * wv + j][lane]);
      s1 += b2f(Az[16 * wv + j][64 + lane]);
    }
    float* ap = agg + (size_t)dprev * Dd;
    atomicAdd(ap + lane, s0);
    atomicAdd(ap + 64 + lane, s1);
  }
}

// -------- per-layer edge kernel (layers 1..): t-PAIR processing — only 2 acc
//          tiles (8 AGPR) live at a time; msg written in place per pair.
//          Az holds only h/msg (GEMM A-operands come from registers). --------
__global__ __launch_bounds__(256, 6) void k_edge_fused(
    const bf16* __restrict__ Z, const bf16* __restrict__ ea_p,
    const int* __restrict__ src_p, const int* __restrict__ dst_p,
    const bf16* __restrict__ h_in,
    const bf16* __restrict__ WpSw, const bf16* __restrict__ WeSw,
    float* agg) {
  __shared__ bf16 Az[64][136];   // h tile -> msg (in place)
  __shared__ int dstS[64];
  int tid = threadIdx.x;
  int lane = tid & 63, wv = tid >> 6;
  int q = lane >> 4, ln = lane & 15;
  int e0 = blockIdx.x * 64;

  if (q == 0) dstS[16 * wv + ln] = dst_p[e0 + 16 * wv + ln];

  short8 af0 = {};
  if (q == 0) af0 = *(const short8*)(ea_p + (size_t)(e0 + 16 * wv + ln) * 8);
  const bf16* zrow = Z + (size_t)(e0 + 16 * wv + ln) * 128 + q * 8;
  short8 zf0 = *(const short8*)(zrow);
  short8 zf1 = *(const short8*)(zrow + 32);
  short8 zf2 = *(const short8*)(zrow + 64);
  short8 zf3 = *(const short8*)(zrow + 96);

  // coalesced h_in gather into own rows of Az
  #pragma unroll
  for (int p = 0; p < 4; ++p) {
    int el = 16 * wv + p * 4 + q;
    int s = src_p[e0 + el];
    uint4 hh = ((const uint4*)h_in)[(size_t)s * 16 + ln];
    *(uint4*)&Az[el][ln * 8] = hh;
  }
  __builtin_amdgcn_wave_barrier();

  // t-pair loop: GEMM0+GEMM2 for 2 output col-groups, then msg in place.
  #pragma unroll
  for (int tp = 0; tp < 4; ++tp) {
    const int t0 = tp * 2, t1 = tp * 2 + 1;
    floatx4 a0 = {}, a1 = {};
    a0 = MFMA16(af0, *(const short8*)(WeSw + ((size_t)t0 * 64 + lane) * 8), a0, 0, 0, 0);
    a1 = MFMA16(af0, *(const short8*)(WeSw + ((size_t)t1 * 64 + lane) * 8), a1, 0, 0, 0);
    a0 = MFMA16(zf0, *(const short8*)(WpSw + ((size_t)(t0) * 64 + lane) * 8), a0, 0, 0, 0);
    a1 = MFMA16(zf0, *(const short8*)(WpSw + ((size_t)(t1) * 64 + lane) * 8), a1, 0, 0, 0);
    a0 = MFMA16(zf1, *(const short8*)(WpSw + ((size_t)(8 + t0) * 64 + lane) * 8), a0, 0, 0, 0);
    a1 = MFMA16(zf1, *(const short8*)(WpSw + ((size_t)(8 + t1) * 64 + lane) * 8), a1, 0, 0, 0);
    a0 = MFMA16(zf2, *(const short8*)(WpSw + ((size_t)(16 + t0) * 64 + lane) * 8), a0, 0, 0, 0);
    a1 = MFMA16(zf2, *(const short8*)(WpSw + ((size_t)(16 + t1) * 64 + lane) * 8), a1, 0, 0, 0);
    a0 = MFMA16(zf3, *(const short8*)(WpSw + ((size_t)(24 + t0) * 64 + lane) * 8), a0, 0, 0, 0);
    a1 = MFMA16(zf3, *(const short8*)(WpSw + ((size_t)(24 + t1) * 64 + lane) * 8), a1, 0, 0, 0);
    int c0 = t0 * 16 + ln, c1 = t1 * 16 + ln;
    #pragma unroll
    for (int r = 0; r < 4; ++r) {
      int el = 16 * wv + q * 4 + r;
      Az[el][c0] = f2b(fmaxf(0.f, a0[r] + b2f(Az[el][c0])));
      Az[el][c1] = f2b(fmaxf(0.f, a1[r] + b2f(Az[el][c1])));
    }
  }
  __builtin_amdgcn_wave_barrier();
  // wave-level segmented sum (dst-sorted)
  {
    float s0 = 0.f, s1 = 0.f;
    int dprev = dstS[16 * wv];
    bool inside = false;
    #pragma unroll
    for (int j = 0; j < 16; ++j) {
      int dcur = dstS[16 * wv + j];
      if (dcur != dprev) {
        float* ap = agg + (size_t)dprev * Dd;
        if (inside) { ap[lane] = s0; ap[64 + lane] = s1; }
        else        { atomicAdd(ap + lane, s0); atomicAdd(ap + 64 + lane, s1); }
        s0 = 0.f; s1 = 0.f; dprev = dcur; inside = true;
      }
      s0 += b2f(Az[16 * wv + j][lane]);
      s1 += b2f(Az[16 * wv + j][64 + lane]);
    }
    float* ap = agg + (size_t)dprev * Dd;
    atomicAdd(ap + lane, s0);
    atomicAdd(ap + 64 + lane, s1);
  }
}

// -------- fused node MLP. GEMM1 split into halves (t=8..15 first: scatters to
//          c>=128 which doesn't clobber staged x at c<128; then t=0..7). GEMM2
//          in quarters. Peak acc regs 32 instead of 96. zero_agg re-zeroes the
//          block's agg rows; vn-add fused into the epilogue. agg may alias out_f
//          (per-block row bands exclusive -> WAR-safe). --------
__global__ __launch_bounds__(256, 4) void k_mlp_fused(
    const bf16* __restrict__ h_in, float* agg,
    const float* __restrict__ eps_arr, int l,
    const int* __restrict__ batch, const float* __restrict__ vn,
    const bf16* __restrict__ W1sw, const float* __restrict__ Msc, const float* __restrict__ Msh,
    const bf16* __restrict__ W2sw, const float* __restrict__ Lsc, const float* __restrict__ Lsh,
    int is_last, int zero_agg, bf16* __restrict__ out_b, float* out_f) {
  __shared__ bf16 R[4][16][280];
  int tid = threadIdx.x;
  int lane = tid & 63, wv = tid >> 6;
  int q = lane >> 4, ln = lane & 15;
  int r0 = blockIdx.x * 64;
  float epsv = 1.0f + eps_arr[l];
  {
    int r = lane >> 2, cc = lane & 3;
    int row = r0 + 16 * wv + r;
    float4 z4 = make_float4(0.f, 0.f, 0.f, 0.f);
    #pragma unroll
    for (int u = 0; u < 4; ++u) {
      int cb = cc * 4 + u;
      U8 o;
      if (row < Nn) {
        U8 hh; hh.u = ((const uint4*)h_in)[row * 16 + cb];
        float4 g0 = ((const float4*)agg)[row * 32 + cb * 2];
        float4 g1 = ((const float4*)agg)[row * 32 + cb * 2 + 1];
        o.h[0] = f2b(epsv * b2f(hh.h[0]) + g0.x); o.h[1] = f2b(epsv * b2f(hh.h[1]) + g0.y);
        o.h[2] = f2b(epsv * b2f(hh.h[2]) + g0.z); o.h[3] = f2b(epsv * b2f(hh.h[3]) + g0.w);
        o.h[4] = f2b(epsv * b2f(hh.h[4]) + g1.x); o.h[5] = f2b(epsv * b2f(hh.h[5]) + g1.y);
        o.h[6] = f2b(epsv * b2f(hh.h[6]) + g1.z); o.h[7] = f2b(epsv * b2f(hh.h[7]) + g1.w);
        if (zero_agg) {
          ((float4*)agg)[row * 32 + cb * 2] = z4;
          ((float4*)agg)[row * 32 + cb * 2 + 1] = z4;
        }
      } else {
        o.u.x = o.u.y = o.u.z = o.u.w = 0;
      }
      *(uint4*)&R[wv][r][cb * 8] = o.u;
    }
  }
  __builtin_amdgcn_wave_barrier();
  // ---- GEMM1 half A: t = 8..15 -> c = 128..255 (staged x at c<128 stays intact)
  {
    floatx4 acc1[8] = {};
    #pragma unroll
    for (int kc = 0; kc < 4; ++kc) {
      short8 af = *(const short8*)&R[wv][ln][kc * 32 + q * 8];
      #pragma unroll
      for (int t8 = 0; t8 < 8; ++t8) {
        int tt = 8 + t8;
        short8 bfr = *(const short8*)(W1sw + (size_t)l * 32768 + (((size_t)kc * 16 + tt) * 64 + lane) * 8);
        acc1[t8] = MFMA16(af, bfr, acc1[t8], 0, 0, 0);
      }
    }
    __builtin_amdgcn_wave_barrier();
    #pragma unroll
    for (int t8 = 0; t8 < 8; ++t8) {
      int c = (8 + t8) * 16 + ln;
      float ss = Msc[c], hh = Msh[c];
      #pragma unroll
      for (int r = 0; r < 4; ++r)
        R[wv][q * 4 + r][c] = f2b(fmaxf(0.f, fmaf(acc1[t8][r], ss, hh)));
    }
  }
  // ---- GEMM1 half B: t = 0..7 -> c = 0..127 (x consumed, then overwritten)
  {
    floatx4 acc1[8] = {};
    #pragma unroll
    for (int kc = 0; kc < 4; ++kc) {
      short8 af = *(const short8*)&R[wv][ln][kc * 32 + q * 8];
      #pragma unroll
      for (int t8 = 0; t8 < 8; ++t8) {
        short8 bfr = *(const short8*)(W1sw + (size_t)l * 32768 + (((size_t)kc * 16 + t8) * 64 + lane) * 8);
        acc1[t8] = MFMA16(af, bfr, acc1[t8], 0, 0, 0);
      }
    }
    __builtin_amdgcn_wave_barrier();
    #pragma unroll
    for (int t8 = 0; t8 < 8; ++t8) {
      int c = t8 * 16 + ln;
      float ss = Msc[c], hh = Msh[c];
      #pragma unroll
      for (int r = 0; r < 4; ++r)
        R[wv][q * 4 + r][c] = f2b(fmaxf(0.f, fmaf(acc1[t8][r], ss, hh)));
    }
  }
  __builtin_amdgcn_wave_barrier();
  // next-layer vn row indices (vn already updated by k_vn_mlp)
  int bb[4] = {0, 0, 0, 0};
  if (!is_last) {
    #pragma unroll
    for (int r = 0; r < 4; ++r) {
      int row = r0 + 16 * wv + q * 4 + r;
      if (row < Nn) bb[r] = batch[row];
    }
  }
  // ---- GEMM2 in quarters (4 output tiles, 16 acc regs at a time)
  #pragma unroll
  for (int g2 = 0; g2 < 2; ++g2) {
    floatx4 acc2[4] = {};
    #pragma unroll
    for (int kc = 0; kc < 8; ++kc) {
      short8 af = *(const short8*)&R[wv][ln][kc * 32 + q * 8];
      #pragma unroll
      for (int t4 = 0; t4 < 4; ++t4) {
        int tt = g2 * 4 + t4;
        short8 bfr = *(const short8*)(W2sw + (size_t)l * 32768 + (((size_t)kc * 8 + tt) * 64 + lane) * 8);
        acc2[t4] = MFMA16(af, bfr, acc2[t4], 0, 0, 0);
      }
    }
    #pragma unroll
    for (int t4 = 0; t4 < 4; ++t4) {
      int tt = g2 * 4 + t4;
      int c = tt * 16 + ln;
      float ss = Lsc[c], hh = Lsh[c];
      #pragma unroll
      for (int r = 0; r < 4; ++r) {
        int row = r0 + 16 * wv + q * 4 + r;
        if (row < Nn) {
          float x = fmaf(acc2[t4][r], ss, hh);
          if (is_last) out_f[(size_t)row * Dd + c] = x;
          else         out_b[(size_t)row * Dd + c] = f2b(fmaxf(0.f, x) + vn[bb[r] * Dd + c]);
        }
      }
    }
  }
}

// -------- vt = segment_sum(h_in, batch) --------
__global__ void k_vt_sum(const bf16* __restrict__ h_in, const int* __restrict__ batch,
                         float* __restrict__ vt) {
  int d = threadIdx.x;
  int chunk = (Nn + gridDim.x - 1) / gridDim.x;
  int r0 = blockIdx.x * chunk;
  int r1 = min(r0 + chunk, Nn);
  if (r0 >= r1) return;
  float acc = 0.f;
  int cur = batch[r0];
  for (int r = r0; r < r1; ++r) {
    int g = batch[r];
    if (g != cur) { atomicAdd(&vt[cur * Dd + d], acc); acc = 0.f; cur = g; }
    acc += b2f(h_in[r * Dd + d]);
  }
  atomicAdd(&vt[cur * Dd + d], acc);
}

// -------- virtual-node MLP (tiny; bn+bias folded) --------
__global__ __launch_bounds__(256) void k_vn_mlp(
    float* __restrict__ vn, const float* __restrict__ vt,
    const float* __restrict__ W1, const float* __restrict__ s1, const float* __restrict__ h1,
    const float* __restrict__ W2, const float* __restrict__ s2, const float* __restrict__ h2) {
  __shared__ float row[128];
  __shared__ float trow[256];
  int g = blockIdx.x;
  int tid = threadIdx.x;
  if (tid < 128) row[tid] = vt[g * Dd + tid] + vn[g * Dd + tid];
  __syncthreads();
  float acc = 0.f;
  for (int k = 0; k < 128; ++k) acc += row[k] * W1[k * 256 + tid];
  trow[tid] = fmaxf(0.f, fmaf(acc, s1[tid], h1[tid]));
  __syncthreads();
  if (tid < 128) {
    float acc2 = 0.f;
    for (int k = 0; k < 256; ++k) acc2 += trow[k] * W2[k * Dd + tid];
    vn[g * Dd + tid] = fmaxf(0.f, fmaf(acc2, s2[tid], h2[tid]));
  }
}

extern "C" void kernel_launch(void* const* d_in, const int* in_sizes, int n_in,
                              void* d_out, int out_size, void* d_ws, size_t ws_size,
                              hipStream_t stream) {
  const int*   x_node    = (const int*)  d_in[0];
  const int*   edge_idx  = (const int*)  d_in[1];
  const float* edge_attr = (const float*)d_in[2];
  const int*   batch     = (const int*)  d_in[3];
  const int*   pos_index = (const int*)  d_in[4];
  const float* pos_enc   = (const float*)d_in[5];
  const int*   pos_batch = (const int*)  d_in[6];
  const float* node_emb  = (const float*)d_in[7];
  const float* z_init    = (const float*)d_in[8];
  const float* ze_bn1    = (const float*)d_in[9];
  const float* ze_W      = (const float*)d_in[10];
  const float* ze_b      = (const float*)d_in[11];
  const float* ze_bn2    = (const float*)d_in[12];
  const float* vn_emb    = (const float*)d_in[13];
  const float* conv_We   = (const float*)d_in[14];
  const float* conv_be   = (const float*)d_in[15];
  const float* conv_Wp   = (const float*)d_in[16];
  const float* conv_bp   = (const float*)d_in[17];
  const float* conv_W1   = (const float*)d_in[18];
  const float* conv_b1   = (const float*)d_in[19];
  const float* conv_bn   = (const float*)d_in[20];
  const float* conv_W2   = (const float*)d_in[21];
  const float* conv_b2   = (const float*)d_in[22];
  const float* conv_eps  = (const float*)d_in[23];
  const float* layer_bn  = (const float*)d_in[24];
  const float* vn_W1     = (const float*)d_in[25];
  const float* vn_b1     = (const float*)d_in[26];
  const float* vn_bn1    = (const float*)d_in[27];
  const float* vn_W2     = (const float*)d_in[28];
  const float* vn_b2     = (const float*)d_in[29];
  const float* vn_bn2    = (const float*)d_in[30];

  // workspace — agg lives in d_out (row-aliased WAR-safe in k_mlp_fused).
  char* wb = (char*)d_ws;
  size_t o = 0;
  auto alloc = [&](size_t bytes) { void* p = wb + o; o += (bytes + 255) & ~255ull; return p; };
  bf16*  h_in     = (bf16*) alloc((size_t)Nn * 128 * 2);
  float* vn       = (float*)alloc((size_t)Gg * 128 * 4);
  float* vt       = (float*)alloc((size_t)Gg * 128 * 4);
  int*   estart   = (int*)  alloc((size_t)(Ee + 1) * 4);
  bf16*  zeWsw    = (bf16*) alloc(16384 * 2);
  bf16*  WpSw     = (bf16*) alloc(49152 * 2);
  bf16*  WeSw     = (bf16*) alloc(12288 * 2);
  bf16*  W1sw     = (bf16*) alloc(98304 * 2);
  bf16*  W2sw     = (bf16*) alloc(98304 * 2);
  float* fb       = (float*)alloc(4352 * 4);
  int*   cnt      = (int*)  alloc((size_t)Nn * 4);
  int*   rs       = (int*)  alloc((size_t)Nn * 4);
  int*   cur      = (int*)  alloc((size_t)Nn * 4);
  int*   chunkSum = (int*)  alloc(128 * 4);
  int*   perm     = (int*)  alloc((size_t)Ee * 4);
  int*   src_p    = (int*)  alloc((size_t)Ee * 4);
  int*   dst_p    = (int*)  alloc((size_t)Ee * 4);
  int2*  rng_p    = (int2*) alloc((size_t)Ee * 8);
  bf16*  ea_p     = (bf16*) alloc((size_t)Ee * 8 * 2);
  bf16*  Z        = (bf16*) alloc((size_t)Ee * 128 * 2);   // 164 MB, allocated last
  float* agg      = (float*)d_out;                          // N*128 f32 == out buffer
  bool useZ = (o <= ws_size);                               // hoisted path only if ws fits

  const int* src = edge_idx;
  const int* dst = edge_idx + Ee;

  // ---- once-per-launch precompute (layer-invariant) ----
  k_estart<<<(Ee + 256) / 256, 256, 0, stream>>>(pos_batch, estart);
  hipMemsetAsync(cnt, 0, (size_t)Nn * 4, stream);
  hipMemsetAsync(cur, 0, (size_t)Nn * 4, stream);
  k_hist<<<(Ee + 255) / 256, 256, 0, stream>>>(dst, cnt);
  int nchunk = (Nn + 1023) / 1024;
  k_scanA<<<nchunk, 1024, 0, stream>>>(cnt, rs, chunkSum);
  k_scanC<<<nchunk, 1024, 0, stream>>>(rs, chunkSum);
  k_scatter<<<(Ee + 255) / 256, 256, 0, stream>>>(dst, rs, cur, perm);
  k_permcopy<<<(Ee + 255) / 256, 256, 0, stream>>>(perm, src, dst, estart, edge_attr,
                                                   src_p, dst_p, rng_p, ea_p);
  k_prep<<<(98304 + 255) / 256, 256, 0, stream>>>(ze_W, conv_Wp, conv_We, conv_be, conv_bp,
                                                  conv_W1, conv_W2,
                                                  zeWsw, WpSw, WeSw, W1sw, W2sw);
  k_bnfold<<<9, 256, 0, stream>>>(ze_bn1, ze_b, ze_bn2, conv_b1, conv_bn,
                                  conv_b2, layer_bn, vn_b1, vn_bn1, vn_b2, vn_bn2, fb);
  k_init_vn<<<(Gg * 128 + 255) / 256, 256, 0, stream>>>(vn_emb, vn);
  k_hin0<<<(Nn * 16 + 255) / 256, 256, 0, stream>>>(x_node, node_emb, vn, batch, h_in);
  hipMemsetAsync(agg, 0, (size_t)Nn * 128 * 4, stream);

  int mblocks = (Nn + 63) / 64;
  for (int l = 0; l < Ll; ++l) {
    if (l == 0 || !useZ)
      k_edge_z<<<Ee / 64, 256, 0, stream>>>(rng_p, pos_index, pos_enc, z_init,
          fb, zeWsw, ea_p, src_p, dst_p, h_in,
          WpSw + (size_t)l * 16384, WeSw + (size_t)l * 4096,
          Z, (l == 0 && useZ) ? 1 : 0, agg);
    else
      k_edge_fused<<<Ee / 64, 256, 0, stream>>>(Z, ea_p, src_p, dst_p, h_in,
          WpSw + (size_t)l * 16384, WeSw + (size_t)l * 4096, agg);
    if (l < Ll - 1) {
      hipMemsetAsync(vt, 0, (size_t)Gg * 128 * 4, stream);
      k_vt_sum<<<1024, 128, 0, stream>>>(h_in, batch, vt);
      k_vn_mlp<<<Gg, 256, 0, stream>>>(vn, vt,
          vn_W1 + (size_t)l * 128 * 256, fb + 2816 + l * 256, fb + 3328 + l * 256,
          vn_W2 + (size_t)l * 256 * 128, fb + 3840 + l * 128, fb + 4096 + l * 128);
    }
    k_mlp_fused<<<mblocks, 256, 0, stream>>>(h_in, agg, conv_eps, l, batch, vn,
        W1sw, fb + 512 + l * 256, fb + 1280 + l * 256,
        W2sw, fb + 2048 + l * 128, fb + 2432 + l * 128,
        (l == Ll - 1) ? 1 : 0, (l < Ll - 1) ? 1 : 0, h_in, (float*)d_out);
  }
}